// Round 1
// baseline (227.756 us; speedup 1.0000x reference)
//
#include <hip/hip_runtime.h>
#include <hip/hip_bf16.h>
#include <cstdint>

typedef __bf16 bf16_t;
typedef __bf16 bf16x8 __attribute__((ext_vector_type(8)));
typedef float f32x4 __attribute__((ext_vector_type(4)));

static constexpr int BM = 128, BN = 128, BK = 32;

__device__ __forceinline__ void g2lds16(const bf16_t* g, bf16_t* l) {
  __builtin_amdgcn_global_load_lds(
      (const __attribute__((address_space(1))) uint32_t*)g,
      (__attribute__((address_space(3))) uint32_t*)l, 16, 0, 0);
}

// f32 -> bf16 cast, 8 elements/thread
__global__ __launch_bounds__(256) void cast_f32_bf16(const float* __restrict__ src,
                                                     bf16_t* __restrict__ dst, int n8) {
  int i = blockIdx.x * 256 + threadIdx.x;
  if (i >= n8) return;
  const float4* s4 = reinterpret_cast<const float4*>(src);
  float4 a = s4[2 * i], b = s4[2 * i + 1];
  bf16x8 o;
  o[0] = (bf16_t)a.x; o[1] = (bf16_t)a.y; o[2] = (bf16_t)a.z; o[3] = (bf16_t)a.w;
  o[4] = (bf16_t)b.x; o[5] = (bf16_t)b.y; o[6] = (bf16_t)b.z; o[7] = (bf16_t)b.w;
  reinterpret_cast<bf16x8*>(dst)[i] = o;
}

// Row softmax over 2048 bf16 elements, in place. One block (256 thr) per row.
__global__ __launch_bounds__(256) void softmax_rows(bf16_t* __restrict__ P) {
  const int t = threadIdx.x, lane = t & 63, wave = t >> 6;
  bf16_t* p = P + (long)blockIdx.x * 2048;
  bf16x8 v = reinterpret_cast<bf16x8*>(p)[t];
  float f[8];
  #pragma unroll
  for (int e = 0; e < 8; e++) f[e] = (float)v[e];
  float m = f[0];
  #pragma unroll
  for (int e = 1; e < 8; e++) m = fmaxf(m, f[e]);
  #pragma unroll
  for (int o = 32; o > 0; o >>= 1) m = fmaxf(m, __shfl_xor(m, o));
  __shared__ float red[4];
  if (lane == 0) red[wave] = m;
  __syncthreads();
  m = fmaxf(fmaxf(red[0], red[1]), fmaxf(red[2], red[3]));
  float s = 0.f;
  #pragma unroll
  for (int e = 0; e < 8; e++) { f[e] = __expf(f[e] - m); s += f[e]; }
  #pragma unroll
  for (int o = 32; o > 0; o >>= 1) s += __shfl_xor(s, o);
  __syncthreads();
  if (lane == 0) red[wave] = s;
  __syncthreads();
  s = red[0] + red[1] + red[2] + red[3];
  const float inv = 1.0f / s;
  #pragma unroll
  for (int e = 0; e < 8; e++) v[e] = (bf16_t)(f[e] * inv);
  reinterpret_cast<bf16x8*>(p)[t] = v;
}

// BT-GEMM: C[m,n] = sum_k A[m,k] * B[n,k]  (both K-contiguous).
// 128x128 tile, BK=32, 4 waves (2x2), each wave 64x64 via 4x4 frags of 16x16x32.
// MODE 0: QKV epilogue (bias add; Q,K row-major bf16; V written transposed to Vt)
// MODE 1: bf16 out, scaled (scores)
// MODE 2: f32 out (final PV)
template<int MODE>
__global__ __launch_bounds__(256) void gemm_bt(
    const bf16_t* __restrict__ A, const bf16_t* __restrict__ B,
    int lda, int ldb, int K, int ldo,
    long sAz, long sBz, long sOz,
    bf16_t* __restrict__ o_q, bf16_t* __restrict__ o_k, bf16_t* __restrict__ o_vt,
    const float* __restrict__ bqp, const float* __restrict__ bkp,
    const float* __restrict__ bvp,
    bf16_t* __restrict__ o_s, float scale,
    float* __restrict__ o_f)
{
  __shared__ bf16_t As[BM * BK];
  __shared__ bf16_t Bs[BN * BK];
  const int t = threadIdx.x;
  const int lane = t & 63, wave = t >> 6;
  const int wr = wave >> 1, wc = wave & 1;
  const int m0 = blockIdx.y * BM, n0 = blockIdx.x * BN;
  const int bz = blockIdx.z;
  A += (long)bz * sAz;
  B += (long)bz * sBz;

  f32x4 acc[4][4];
  #pragma unroll
  for (int i = 0; i < 4; i++)
    #pragma unroll
    for (int j = 0; j < 4; j++) { f32x4 z = {0.f, 0.f, 0.f, 0.f}; acc[i][j] = z; }

  // staging: thread t loads 16B; LDS layout linear in thread order (wave-uniform + lane*16)
  const int srow = t >> 2;          // 0..63
  const int scol = (t & 3) * 8;     // 0/8/16/24
  const bf16_t* Ag = A + (long)(m0 + srow) * lda + scol;
  const bf16_t* Bg = B + (long)(n0 + srow) * ldb + scol;
  bf16_t* Asl = &As[srow * BK + scol];
  bf16_t* Bsl = &Bs[srow * BK + scol];

  // MFMA fragment addresses: lane holds row (lane&15), 8 contiguous k at (lane>>4)*8
  const int fr = lane & 15;
  const int ko = (lane >> 4) * 8;
  const bf16_t* Af = &As[(wr * 64 + fr) * BK + ko];
  const bf16_t* Bf = &Bs[(wc * 64 + fr) * BK + ko];

  for (int k0 = 0; k0 < K; k0 += BK) {
    g2lds16(Ag + k0, Asl);
    g2lds16(Ag + (long)64 * lda + k0, Asl + 64 * BK);
    g2lds16(Bg + k0, Bsl);
    g2lds16(Bg + (long)64 * ldb + k0, Bsl + 64 * BK);
    __syncthreads();
    bf16x8 af[4], bf[4];
    #pragma unroll
    for (int i = 0; i < 4; i++) af[i] = *reinterpret_cast<const bf16x8*>(Af + i * 16 * BK);
    #pragma unroll
    for (int j = 0; j < 4; j++) bf[j] = *reinterpret_cast<const bf16x8*>(Bf + j * 16 * BK);
    #pragma unroll
    for (int i = 0; i < 4; i++)
      #pragma unroll
      for (int j = 0; j < 4; j++)
        acc[i][j] = __builtin_amdgcn_mfma_f32_16x16x32_bf16(af[i], bf[j], acc[i][j], 0, 0, 0);
    __syncthreads();
  }

  // C/D layout: col = lane&15, row = (lane>>4)*4 + r
  const int er = (lane >> 4) * 4;
  const int ec = lane & 15;
  #pragma unroll
  for (int i = 0; i < 4; i++) {
    const int mg = m0 + wr * 64 + i * 16 + er;
    #pragma unroll
    for (int j = 0; j < 4; j++) {
      const int ng = n0 + wc * 64 + j * 16 + ec;
      if constexpr (MODE == 0) {
        if (ng < 1024) {
          const float bb = bqp[ng];
          #pragma unroll
          for (int r = 0; r < 4; r++)
            o_q[(long)(mg + r) * 1024 + ng] = (bf16_t)(acc[i][j][r] + bb);
        } else if (ng < 2048) {
          const int nn = ng - 1024;
          const float bb = bkp[nn];
          #pragma unroll
          for (int r = 0; r < 4; r++)
            o_k[(long)(mg + r) * 1024 + nn] = (bf16_t)(acc[i][j][r] + bb);
        } else {
          const int nn = ng - 2048;
          const float bb = bvp[nn];
          const int bat = mg >> 11, sr = mg & 2047;   // batch, seq pos (tiles never span batches)
          union { bf16_t h[4]; uint2 u; } pk;
          #pragma unroll
          for (int r = 0; r < 4; r++) pk.h[r] = (bf16_t)(acc[i][j][r] + bb);
          // Vt[b][nn][sr..sr+3] — 8B packed store
          *reinterpret_cast<uint2*>(&o_vt[((long)bat * 1024 + nn) * 2048 + sr]) = pk.u;
        }
      } else if constexpr (MODE == 1) {
        bf16_t* os = o_s + (long)bz * sOz;
        #pragma unroll
        for (int r = 0; r < 4; r++)
          os[(long)(mg + r) * ldo + ng] = (bf16_t)(acc[i][j][r] * scale);
      } else {
        float* of = o_f + (long)bz * sOz;
        #pragma unroll
        for (int r = 0; r < 4; r++)
          of[(long)(mg + r) * ldo + ng] = acc[i][j][r];
      }
    }
  }
}

extern "C" void kernel_launch(void* const* d_in, const int* in_sizes, int n_in,
                              void* d_out, int out_size, void* d_ws, size_t ws_size,
                              hipStream_t stream) {
  const float* X  = (const float*)d_in[0];
  const float* Wq = (const float*)d_in[1];
  const float* bq = (const float*)d_in[2];
  const float* Wk = (const float*)d_in[3];
  const float* bk = (const float*)d_in[4];
  const float* Wv = (const float*)d_in[5];
  const float* bv = (const float*)d_in[6];
  float* out = (float*)d_out;

  // ws layout (80 MiB needed):
  // [0:16M)  Q bf16  [8192,1024]
  // [16:32M) K bf16  [8192,1024]
  // [32:48M) Vt bf16 [4,1024,2048]   (V transposed per batch)
  // [48:64M) Xb bf16 [8192,1024]     (dead after QKV GEMM)
  // [64:70M) Wc bf16 [3072,1024]     (dead after QKV GEMM)
  // [48:80M) P bf16  [4,2048,2048]   (overlays Xb+Wc)
  constexpr long SEG = 16777216;
  char* ws = (char*)d_ws;
  bf16_t* Q  = (bf16_t*)(ws + 0 * SEG);
  bf16_t* Kc = (bf16_t*)(ws + 1 * SEG);
  bf16_t* Vt = (bf16_t*)(ws + 2 * SEG);
  bf16_t* Xb = (bf16_t*)(ws + 3 * SEG);
  bf16_t* Wc = (bf16_t*)(ws + 4 * SEG);
  bf16_t* P  = (bf16_t*)(ws + 3 * SEG);

  cast_f32_bf16<<<4096, 256, 0, stream>>>(X,  Xb, 1048576);
  cast_f32_bf16<<<512,  256, 0, stream>>>(Wq, Wc,           131072);
  cast_f32_bf16<<<512,  256, 0, stream>>>(Wk, Wc + 1048576, 131072);
  cast_f32_bf16<<<512,  256, 0, stream>>>(Wv, Wc + 2097152, 131072);

  dim3 blk(256);
  {  // QKV: M=8192, N=3072, K=1024
    dim3 g(3072 / BN, 8192 / BM, 1);
    gemm_bt<0><<<g, blk, 0, stream>>>(Xb, Wc, 1024, 1024, 1024, 0, 0, 0, 0,
                                      Q, Kc, Vt, bq, bk, bv, nullptr, 0.f, nullptr);
  }
  {  // scores: per batch M=N=2048, K=1024; P = (Q K^T)/32 in bf16
    dim3 g(2048 / BN, 2048 / BM, 4);
    gemm_bt<1><<<g, blk, 0, stream>>>(Q, Kc, 1024, 1024, 1024, 2048,
                                      2097152, 2097152, 4194304,
                                      nullptr, nullptr, nullptr, nullptr, nullptr, nullptr,
                                      P, 0.03125f, nullptr);
  }
  softmax_rows<<<8192, 256, 0, stream>>>(P);
  {  // PV: per batch M=2048, N=1024, K=2048 -> f32 out
    dim3 g(1024 / BN, 2048 / BM, 4);
    gemm_bt<2><<<g, blk, 0, stream>>>(P, Vt, 2048, 2048, 2048, 1024,
                                      4194304, 2097152, 2097152,
                                      nullptr, nullptr, nullptr, nullptr, nullptr, nullptr,
                                      nullptr, 0.f, out);
  }
}

// Round 2
// 199.182 us; speedup vs baseline: 1.1435x; 1.1435x over previous
//
#include <hip/hip_runtime.h>
#include <hip/hip_bf16.h>
#include <cstdint>

typedef __bf16 bf16_t;
typedef __bf16 bf16x8 __attribute__((ext_vector_type(8)));
typedef float f32x4 __attribute__((ext_vector_type(4)));

__device__ __forceinline__ void g2lds16(const bf16_t* g, bf16_t* l) {
  __builtin_amdgcn_global_load_lds(
      (const __attribute__((address_space(1))) uint32_t*)g,
      (__attribute__((address_space(3))) uint32_t*)l, 16, 0, 0);
}

// f32 -> bf16 cast, 8 elements/thread
__global__ __launch_bounds__(256) void cast_f32_bf16(const float* __restrict__ src,
                                                     bf16_t* __restrict__ dst, int n8) {
  int i = blockIdx.x * 256 + threadIdx.x;
  if (i >= n8) return;
  const float4* s4 = reinterpret_cast<const float4*>(src);
  float4 a = s4[2 * i], b = s4[2 * i + 1];
  bf16x8 o;
  o[0] = (bf16_t)a.x; o[1] = (bf16_t)a.y; o[2] = (bf16_t)a.z; o[3] = (bf16_t)a.w;
  o[4] = (bf16_t)b.x; o[5] = (bf16_t)b.y; o[6] = (bf16_t)b.z; o[7] = (bf16_t)b.w;
  reinterpret_cast<bf16x8*>(dst)[i] = o;
}

// Row softmax over 2048 bf16 elements, in place. One block (256 thr) per row.
__global__ __launch_bounds__(256) void softmax_rows(bf16_t* __restrict__ P) {
  const int t = threadIdx.x, lane = t & 63, wave = t >> 6;
  bf16_t* p = P + (long)blockIdx.x * 2048;
  bf16x8 v = reinterpret_cast<bf16x8*>(p)[t];
  float f[8];
  #pragma unroll
  for (int e = 0; e < 8; e++) f[e] = (float)v[e];
  float m = f[0];
  #pragma unroll
  for (int e = 1; e < 8; e++) m = fmaxf(m, f[e]);
  #pragma unroll
  for (int o = 32; o > 0; o >>= 1) m = fmaxf(m, __shfl_xor(m, o));
  __shared__ float red[4];
  if (lane == 0) red[wave] = m;
  __syncthreads();
  m = fmaxf(fmaxf(red[0], red[1]), fmaxf(red[2], red[3]));
  float s = 0.f;
  #pragma unroll
  for (int e = 0; e < 8; e++) { f[e] = __expf(f[e] - m); s += f[e]; }
  #pragma unroll
  for (int o = 32; o > 0; o >>= 1) s += __shfl_xor(s, o);
  __syncthreads();
  if (lane == 0) red[wave] = s;
  __syncthreads();
  s = red[0] + red[1] + red[2] + red[3];
  const float inv = 1.0f / s;
  #pragma unroll
  for (int e = 0; e < 8; e++) v[e] = (bf16_t)(f[e] * inv);
  reinterpret_cast<bf16x8*>(p)[t] = v;
}

// ---------------------------------------------------------------------------
// 256x256 8-phase BT-GEMM (BK=64, 512 threads = 8 waves as 2x4).
// C[m,n] = sum_k A[m,k]*B[n,k]. Per-wave output: rows {mh*128+wr*64+0..63} x
// cols {nh*128+wc*32+0..31} so quadrant (mh,nh) reads only stage-half mh of A
// and nh of B -> race-free half-tile prefetch with counted vmcnt(4).
// LDS swizzle: byte ^= ((row&7)<<4), applied on pre-swizzled global source
// (linear LDS dest for global_load_lds) and on ds_read addresses.
// MODE 0: QKV epilogue (bias; Q,K row-major bf16; V transposed to Vt)
// MODE 1: bf16 out, scaled (scores);  MODE 2: f32 out (PV)
// ---------------------------------------------------------------------------
template<int MODE>
__global__ __launch_bounds__(512, 2) void gemm8p(
    const bf16_t* __restrict__ A, const bf16_t* __restrict__ B,
    int lda, int ldb, int K, int ldo,
    long sAz, long sBz, long sOz,
    bf16_t* __restrict__ o_q, bf16_t* __restrict__ o_k, bf16_t* __restrict__ o_vt,
    const float* __restrict__ bqp, const float* __restrict__ bkp, const float* __restrict__ bvp,
    bf16_t* __restrict__ o_s, float scale, float* __restrict__ o_f)
{
  __shared__ bf16_t As[2][16384];   // [buf][256 rows x 64 cols]
  __shared__ bf16_t Bs[2][16384];
  const int t = threadIdx.x;
  const int lane = t & 63;
  const int wave = t >> 6;
  const int wr = wave >> 2, wc = wave & 3;
  const int m0 = blockIdx.y * 256, n0 = blockIdx.x * 256;
  const int bz = blockIdx.z;
  A += (long)bz * sAz;
  B += (long)bz * sBz;

  // staging constants: thread t writes LDS bytes [region + t*16, +16)
  // pre-swizzled source col so that LDS[o] = G[swz(o)], swz(b)=b^(((b>>7)&7)<<4)
  const int srow = t >> 3;                                    // 0..63
  const int scolB = (((t & 7) << 4) ^ ((srow & 7) << 4));     // byte col 0..127
  const bf16_t* Abase = A + (long)m0 * lda + (scolB >> 1);
  const bf16_t* Bbase = B + (long)n0 * ldb + (scolB >> 1);

  // fragment-read constants
  const int laneRow = lane & 15;
  const int laneK16 = (lane >> 4) << 4;     // byte offset of this lane's 8-elem k-group
  const int rflip = (laneRow & 7) << 4;
  const char* AsB = (const char*)&As[0][0];
  const char* BsB = (const char*)&Bs[0][0];

  f32x4 acc[8][4];
  #pragma unroll
  for (int i = 0; i < 8; ++i)
    #pragma unroll
    for (int j = 0; j < 4; ++j) { f32x4 z = {0.f, 0.f, 0.f, 0.f}; acc[i][j] = z; }

#define STAGE_A(bb, h, kt) do { \
    const bf16_t* _s = Abase + (long)((h) * 128 + srow) * lda + (kt) * 64; \
    g2lds16(_s, &As[bb][(h) * 8192 + t * 8]); \
    g2lds16(_s + (long)64 * lda, &As[bb][(h) * 8192 + 4096 + t * 8]); \
  } while (0)
#define STAGE_B(bb, h, kt) do { \
    const bf16_t* _s = Bbase + (long)((h) * 128 + srow) * ldb + (kt) * 64; \
    g2lds16(_s, &Bs[bb][(h) * 8192 + t * 8]); \
    g2lds16(_s + (long)64 * ldb, &Bs[bb][(h) * 8192 + 4096 + t * 8]); \
  } while (0)

  bf16x8 a[4][2], b[2][2];

#define LOADA(mh, bc) do { \
    _Pragma("unroll") \
    for (int fi2 = 0; fi2 < 4; ++fi2) { \
      const int row = (mh) * 128 + wr * 64 + fi2 * 16 + laneRow; \
      _Pragma("unroll") \
      for (int ks = 0; ks < 2; ++ks) { \
        const int off = ((bc) * 32768 + (row << 7) + (ks << 6) + laneK16) ^ rflip; \
        a[fi2][ks] = *reinterpret_cast<const bf16x8*>(AsB + off); \
      } \
    } \
  } while (0)
#define LOADB(nh, bc) do { \
    _Pragma("unroll") \
    for (int fj2 = 0; fj2 < 2; ++fj2) { \
      const int row = (nh) * 128 + wc * 32 + fj2 * 16 + laneRow; \
      _Pragma("unroll") \
      for (int ks = 0; ks < 2; ++ks) { \
        const int off = ((bc) * 32768 + (row << 7) + (ks << 6) + laneK16) ^ rflip; \
        b[fj2][ks] = *reinterpret_cast<const bf16x8*>(BsB + off); \
      } \
    } \
  } while (0)
#define QUAD(mh, nh) do { \
    _Pragma("unroll") \
    for (int fi2 = 0; fi2 < 4; ++fi2) \
      _Pragma("unroll") \
      for (int ks = 0; ks < 2; ++ks) \
        _Pragma("unroll") \
        for (int fj2 = 0; fj2 < 2; ++fj2) \
          acc[(mh) * 4 + fi2][(nh) * 2 + fj2] = __builtin_amdgcn_mfma_f32_16x16x32_bf16( \
              a[fi2][ks], b[fj2][ks], acc[(mh) * 4 + fi2][(nh) * 2 + fj2], 0, 0, 0); \
  } while (0)
#define PH_MID() do { \
    __builtin_amdgcn_s_barrier(); \
    asm volatile("s_waitcnt lgkmcnt(0)" ::: "memory"); \
    __builtin_amdgcn_sched_barrier(0); \
    __builtin_amdgcn_s_setprio(1); \
  } while (0)
#define PH_END() do { \
    __builtin_amdgcn_s_setprio(0); \
    __builtin_amdgcn_s_barrier(); \
  } while (0)
#define PH_ENDV() do { \
    __builtin_amdgcn_s_setprio(0); \
    asm volatile("s_waitcnt vmcnt(4)" ::: "memory"); \
    __builtin_amdgcn_s_barrier(); \
  } while (0)

  const int NT = K >> 6;
  const int NITER = K >> 7;

  // prologue: tile0 (buf0) fully + tile1 (buf1) halves 0
  STAGE_A(0, 0, 0);
  STAGE_B(0, 0, 0);
  STAGE_A(0, 1, 0);
  STAGE_B(0, 1, 0);
  STAGE_A(1, 0, 1);
  STAGE_B(1, 0, 1);
  asm volatile("s_waitcnt vmcnt(4)" ::: "memory");
  __builtin_amdgcn_s_barrier();

  for (int it = 0; it < NITER; ++it) {
    const int T1 = 2 * it + 1;
    int T2 = 2 * it + 2; if (T2 >= NT) T2 = NT - 1;   // clamped prefetch (garbage,
    int T3 = 2 * it + 3; if (T3 >= NT) T3 = NT - 1;   // never computed) keeps vmcnt exact
    // p0: quad(0,0) from buf0; stage T1.A1
    LOADA(0, 0); LOADB(0, 0);
    STAGE_A(1, 1, T1);
    PH_MID(); QUAD(0, 0); PH_END();
    // p1: quad(0,1); stage T1.B1
    LOADB(1, 0);
    STAGE_B(1, 1, T1);
    PH_MID(); QUAD(0, 1); PH_END();
    // p2: quad(1,0); stage T2.A0
    LOADA(1, 0); LOADB(0, 0);
    STAGE_A(0, 0, T2);
    PH_MID(); QUAD(1, 0); PH_END();
    // p3: quad(1,1); stage T2.B0; counted wait for T1
    LOADB(1, 0);
    STAGE_B(0, 0, T2);
    PH_MID(); QUAD(1, 1); PH_ENDV();
    // p4: quad(0,0) from buf1; stage T2.A1
    LOADA(0, 1); LOADB(0, 1);
    STAGE_A(0, 1, T2);
    PH_MID(); QUAD(0, 0); PH_END();
    // p5: quad(0,1); stage T2.B1
    LOADB(1, 1);
    STAGE_B(0, 1, T2);
    PH_MID(); QUAD(0, 1); PH_END();
    // p6: quad(1,0); stage T3.A0
    LOADA(1, 1); LOADB(0, 1);
    STAGE_A(1, 0, T3);
    PH_MID(); QUAD(1, 0); PH_END();
    // p7: quad(1,1); stage T3.B0; counted wait for T2
    LOADB(1, 1);
    STAGE_B(1, 0, T3);
    PH_MID(); QUAD(1, 1); PH_ENDV();
  }

  // epilogue: C/D frag layout col=lane&15, row=(lane>>4)*4+r
  const int er = (lane >> 4) << 2;
  const int ec = lane & 15;
  #pragma unroll
  for (int mh = 0; mh < 2; ++mh)
  #pragma unroll
  for (int fi2 = 0; fi2 < 4; ++fi2) {
    const int mg = m0 + mh * 128 + wr * 64 + fi2 * 16 + er;
    #pragma unroll
    for (int nh = 0; nh < 2; ++nh)
    #pragma unroll
    for (int fj2 = 0; fj2 < 2; ++fj2) {
      const int ng = n0 + nh * 128 + wc * 32 + fj2 * 16 + ec;
      const f32x4 v = acc[mh * 4 + fi2][nh * 2 + fj2];
      if constexpr (MODE == 0) {
        if (ng < 1024) {
          const float bb = bqp[ng];
          #pragma unroll
          for (int r = 0; r < 4; ++r)
            o_q[(long)(mg + r) * 1024 + ng] = (bf16_t)(v[r] + bb);
        } else if (ng < 2048) {
          const int nn = ng - 1024;
          const float bb = bkp[nn];
          #pragma unroll
          for (int r = 0; r < 4; ++r)
            o_k[(long)(mg + r) * 1024 + nn] = (bf16_t)(v[r] + bb);
        } else {
          const int nn = ng - 2048;
          const float bb = bvp[nn];
          const int bat = mg >> 11, sr = mg & 2047;
          union { bf16_t h[4]; uint2 u; } pk;
          #pragma unroll
          for (int r = 0; r < 4; ++r) pk.h[r] = (bf16_t)(v[r] + bb);
          *reinterpret_cast<uint2*>(&o_vt[((long)bat * 1024 + nn) * 2048 + sr]) = pk.u;
        }
      } else if constexpr (MODE == 1) {
        bf16_t* os = o_s + (long)bz * sOz;
        #pragma unroll
        for (int r = 0; r < 4; ++r)
          os[(long)(mg + r) * ldo + ng] = (bf16_t)(v[r] * scale);
      } else {
        float* of = o_f + (long)bz * sOz;
        #pragma unroll
        for (int r = 0; r < 4; ++r)
          of[(long)(mg + r) * ldo + ng] = v[r];
      }
    }
  }
#undef STAGE_A
#undef STAGE_B
#undef LOADA
#undef LOADB
#undef QUAD
#undef PH_MID
#undef PH_END
#undef PH_ENDV
}

extern "C" void kernel_launch(void* const* d_in, const int* in_sizes, int n_in,
                              void* d_out, int out_size, void* d_ws, size_t ws_size,
                              hipStream_t stream) {
  const float* X  = (const float*)d_in[0];
  const float* Wq = (const float*)d_in[1];
  const float* bq = (const float*)d_in[2];
  const float* Wk = (const float*)d_in[3];
  const float* bk = (const float*)d_in[4];
  const float* Wv = (const float*)d_in[5];
  const float* bv = (const float*)d_in[6];
  float* out = (float*)d_out;

  // ws layout (80 MiB):
  // [0:16M) Q bf16 [8192,1024] | [16:32M) K bf16 | [32:48M) Vt bf16 [4,1024,2048]
  // [48:64M) Xb bf16 | [64:70M) Wc bf16 [3072,1024] | [48:80M) P bf16 [4,2048,2048]
  constexpr long SEG = 16777216;
  char* ws = (char*)d_ws;
  bf16_t* Q  = (bf16_t*)(ws + 0 * SEG);
  bf16_t* Kc = (bf16_t*)(ws + 1 * SEG);
  bf16_t* Vt = (bf16_t*)(ws + 2 * SEG);
  bf16_t* Xb = (bf16_t*)(ws + 3 * SEG);
  bf16_t* Wc = (bf16_t*)(ws + 4 * SEG);
  bf16_t* P  = (bf16_t*)(ws + 3 * SEG);

  cast_f32_bf16<<<4096, 256, 0, stream>>>(X,  Xb, 1048576);
  cast_f32_bf16<<<512,  256, 0, stream>>>(Wq, Wc,           131072);
  cast_f32_bf16<<<512,  256, 0, stream>>>(Wk, Wc + 1048576, 131072);
  cast_f32_bf16<<<512,  256, 0, stream>>>(Wv, Wc + 2097152, 131072);

  dim3 blk(512);
  {  // QKV: M=8192, N=3072, K=1024
    dim3 g(3072 / 256, 8192 / 256, 1);
    gemm8p<0><<<g, blk, 0, stream>>>(Xb, Wc, 1024, 1024, 1024, 1024, 0, 0, 0,
                                     Q, Kc, Vt, bq, bk, bv, nullptr, 0.f, nullptr);
  }
  {  // scores: per batch M=N=2048, K=1024; P = (Q K^T)/32 in bf16
    dim3 g(2048 / 256, 2048 / 256, 4);
    gemm8p<1><<<g, blk, 0, stream>>>(Q, Kc, 1024, 1024, 1024, 2048,
                                     2097152, 2097152, 4194304,
                                     nullptr, nullptr, nullptr, nullptr, nullptr, nullptr,
                                     P, 0.03125f, nullptr);
  }
  softmax_rows<<<8192, 256, 0, stream>>>(P);
  {  // PV: per batch M=2048, N=1024, K=2048 -> f32 out
    dim3 g(1024 / 256, 2048 / 256, 4);
    gemm8p<2><<<g, blk, 0, stream>>>(P, Vt, 2048, 2048, 2048, 1024,
                                     4194304, 2097152, 2097152,
                                     nullptr, nullptr, nullptr, nullptr, nullptr, nullptr,
                                     nullptr, 0.f, out);
  }
}